// Round 1
// baseline (94.998 us; speedup 1.0000x reference)
//
#include <hip/hip_runtime.h>
#include <stdint.h>

typedef __bf16 bf16;
typedef bf16 bf16x8 __attribute__((ext_vector_type(8)));
typedef float floatx4 __attribute__((ext_vector_type(4)));

#define INV_T 2.0f   // 1 / TEMPERATURE, TEMPERATURE = 0.5

// ---------------------------------------------------------------------------
// Kernel 1: L2-normalize each row of proj_1 / proj_2 (fp32), write bf16 reps.
// One wave (64 lanes) per row of 128 floats; 2 elements/lane.
// ---------------------------------------------------------------------------
__global__ __launch_bounds__(256) void nrm_kernel(const float* __restrict__ p1,
                                                  const float* __restrict__ p2,
                                                  unsigned* __restrict__ reps) {
    int gt   = blockIdx.x * 256 + threadIdx.x;
    int row  = gt >> 6;
    int lane = gt & 63;
    const float* srcRow = (row < 4096) ? (p1 + (size_t)row * 128)
                                       : (p2 + (size_t)(row - 4096) * 128);
    float2 v = ((const float2*)srcRow)[lane];
    float ss = v.x * v.x + v.y * v.y;
#pragma unroll
    for (int s = 1; s < 64; s <<= 1) ss += __shfl_xor(ss, s, 64);
    float inv = 1.0f / fmaxf(sqrtf(ss), 1e-12f);
    union { bf16 h[2]; unsigned u; } pk;
    pk.h[0] = (bf16)(v.x * inv);
    pk.h[1] = (bf16)(v.y * inv);
    reps[(size_t)row * 64 + lane] = pk.u;   // row-major [8192][128] bf16
}

// ---------------------------------------------------------------------------
// Kernel 2: for each row i, rowsum[i] = sum_{j != i} exp(2*dot(r_i, r_j)),
// and pos[i] = dot(r_i, r_{(i+4096) mod 8192}).
// Grid: (8 col-groups of 1024, 64 row-tiles of 128). Block = 256 = 4 waves.
// A-tile (128x128 bf16) LDS-resident + A-frags in registers; loop 8 B-tiles.
// ---------------------------------------------------------------------------
__global__ __launch_bounds__(256, 2) void sim_kernel(const bf16* __restrict__ reps,
                                                     float* __restrict__ rowsum,
                                                     float* __restrict__ pos) {
    __shared__ bf16 lA[128 * 128];   // 32 KB
    __shared__ bf16 lB[128 * 128];   // 32 KB

    const int cg   = blockIdx.x;   // 0..7
    const int bi   = blockIdx.y;   // 0..63
    const int tid  = threadIdx.x;
    const int w    = tid >> 6;     // wave 0..3
    const int lane = tid & 63;
    const int quad = lane >> 4;
    const int lcol = lane & 15;

    const int rowTileBase = bi * 128;

    // stage A tile: LDS layout identical to global row-major -> flat copy
    {
        const uint4* gA = (const uint4*)(reps + (size_t)rowTileBase * 128);
        uint4* sA = (uint4*)lA;
#pragma unroll
        for (int i = 0; i < 8; i++) sA[i * 256 + tid] = gA[i * 256 + tid];
    }
    __syncthreads();

    // wave's 64x64 quadrant of the 128x128 output tile
    const int wRow = (w >> 1) * 64;
    const int wCol = (w & 1) * 64;

    // preload A fragments (constant across the 8 B-tiles)
    // A-frag layout: lane holds A[m = lane&15][k = quad*8 + j], j=0..7
    bf16x8 aF[4][4];
#pragma unroll
    for (int mi = 0; mi < 4; mi++)
#pragma unroll
        for (int ks = 0; ks < 4; ks++) {
            int r = wRow + mi * 16 + lcol;
            int k = ks * 32 + quad * 8;
            aF[mi][ks] = *(const bf16x8*)&lA[r * 128 + k];
        }

    float rs[16];   // per-lane rowsum partials, index = mi*4 + reg
#pragma unroll
    for (int i = 0; i < 16; i++) rs[i] = 0.0f;

    for (int cj = 0; cj < 8; cj++) {
        const int colTileBase = cg * 1024 + cj * 128;
        __syncthreads();   // previous iteration's lB reads complete
        {
            const uint4* gB = (const uint4*)(reps + (size_t)colTileBase * 128);
            uint4* sB = (uint4*)lB;
#pragma unroll
            for (int i = 0; i < 8; i++) sB[i * 256 + tid] = gB[i * 256 + tid];
        }
        __syncthreads();

        floatx4 acc[4][4];
        const floatx4 zf = {0.0f, 0.0f, 0.0f, 0.0f};
#pragma unroll
        for (int mi = 0; mi < 4; mi++)
#pragma unroll
            for (int ni = 0; ni < 4; ni++) acc[mi][ni] = zf;

#pragma unroll
        for (int ks = 0; ks < 4; ks++) {
#pragma unroll
            for (int ni = 0; ni < 4; ni++) {
                int c = wCol + ni * 16 + lcol;
                int k = ks * 32 + quad * 8;
                bf16x8 bF = *(const bf16x8*)&lB[c * 128 + k];
#pragma unroll
                for (int mi = 0; mi < 4; mi++)
                    acc[mi][ni] = __builtin_amdgcn_mfma_f32_16x16x32_bf16(
                        aF[mi][ks], bF, acc[mi][ni], 0, 0, 0);
            }
        }

        // fused epilogue: exp + rowsum partials (+ diag exclusion / pos grab)
        const int rowB = rowTileBase + wRow;
        const int colB = colTileBase + wCol;
        const bool diagT = (colTileBase == rowTileBase);
        const bool partT = (colTileBase == ((rowTileBase + 4096) & 8191));
        if (diagT | partT) {
#pragma unroll
            for (int mi = 0; mi < 4; mi++)
#pragma unroll
                for (int ni = 0; ni < 4; ni++)
#pragma unroll
                    for (int r = 0; r < 4; r++) {
                        int grow = rowB + mi * 16 + quad * 4 + r;
                        int gcol = colB + ni * 16 + lcol;
                        float s = acc[mi][ni][r];
                        if (partT && gcol == ((grow + 4096) & 8191)) pos[grow] = s;
                        float e = __expf(s * INV_T);
                        if (diagT && grow == gcol) e = 0.0f;   // mask j == i
                        rs[mi * 4 + r] += e;
                    }
        } else {
#pragma unroll
            for (int mi = 0; mi < 4; mi++)
#pragma unroll
                for (int ni = 0; ni < 4; ni++)
#pragma unroll
                    for (int r = 0; r < 4; r++)
                        rs[mi * 4 + r] += __expf(acc[mi][ni][r] * INV_T);
        }
    }

    // reduce rowsum partials across the 16 lanes of each quad (same rows)
#pragma unroll
    for (int s = 1; s < 16; s <<= 1)
#pragma unroll
        for (int k = 0; k < 16; k++) rs[k] += __shfl_xor(rs[k], s, 64);

    if (lcol == 0) {
#pragma unroll
        for (int k = 0; k < 16; k++) {
            int grow = rowTileBase + wRow + (k >> 2) * 16 + quad * 4 + (k & 3);
            atomicAdd(&rowsum[grow], rs[k]);   // 8 adds/address total
        }
    }
}

// ---------------------------------------------------------------------------
// Kernel 3: loss = (1/8192) * sum_i [ log(rowsum_i) - 2*pos_i ]
// ---------------------------------------------------------------------------
__global__ __launch_bounds__(256) void fin_kernel(const float* __restrict__ rowsum,
                                                  const float* __restrict__ pos,
                                                  float* __restrict__ out) {
    int r = blockIdx.x * 256 + threadIdx.x;
    float v = logf(rowsum[r]) - pos[r] * INV_T;
#pragma unroll
    for (int s = 1; s < 64; s <<= 1) v += __shfl_xor(v, s, 64);
    __shared__ float red[4];
    if ((threadIdx.x & 63) == 0) red[threadIdx.x >> 6] = v;
    __syncthreads();
    if (threadIdx.x == 0) {
        float t = (red[0] + red[1]) + (red[2] + red[3]);
        atomicAdd(out, t * (1.0f / 8192.0f));
    }
}

extern "C" void kernel_launch(void* const* d_in, const int* in_sizes, int n_in,
                              void* d_out, int out_size, void* d_ws, size_t ws_size,
                              hipStream_t stream) {
    const float* p1 = (const float*)d_in[0];
    const float* p2 = (const float*)d_in[1];
    float* out = (float*)d_out;

    char* ws     = (char*)d_ws;
    bf16* reps   = (bf16*)ws;                              // 8192*128*2 = 2 MB
    float* rowsum = (float*)(ws + (2u << 20));             // 32 KB
    float* pos    = (float*)(ws + (2u << 20) + (32u << 10)); // 32 KB

    hipMemsetAsync(rowsum, 0, 8192 * sizeof(float), stream);
    hipMemsetAsync(out, 0, sizeof(float), stream);

    nrm_kernel<<<2048, 256, 0, stream>>>(p1, p2, (unsigned*)reps);
    sim_kernel<<<dim3(8, 64), 256, 0, stream>>>(reps, rowsum, pos);
    fin_kernel<<<32, 256, 0, stream>>>(rowsum, pos, out);
}